// Round 14
// baseline (552.014 us; speedup 1.0000x reference)
//
#include <hip/hip_runtime.h>
#include <hip/hip_bf16.h>
#include <stdint.h>
#include <stddef.h>

typedef __hip_bfloat16 bf16;
typedef __attribute__((ext_vector_type(8))) __bf16 bf16x8;
typedef __attribute__((ext_vector_type(4))) float f32x4;
typedef __attribute__((ext_vector_type(4))) unsigned int u32x4;

__device__ __forceinline__ bf16 f2b(float x) { return __float2bfloat16(x); }
__device__ __forceinline__ uint32_t b16bits(float x) {
    union { bf16 h; unsigned short u; } cv; cv.h = __float2bfloat16(x); return (uint32_t)cv.u;
}

// async global->LDS copy, 16B per lane. LDS dest must be wave-uniform base + lane*16.
__device__ __forceinline__ void async_copy16(const bf16* g, bf16* l) {
    __builtin_amdgcn_global_load_lds(
        (const __attribute__((address_space(1))) unsigned int*)g,
        (__attribute__((address_space(3))) unsigned int*)l,
        16, 0, 0);
}

// XCD-aware remap: blocks dispatch round-robin to 8 XCDs by l%8. Map each group of
// 64 consecutive l to 8 m-tiles x 8 n-tiles so the 8 blocks of one XCD share ONE
// m-tile -> A row-tile fetched once into that XCD's L2.
__device__ __forceinline__ void remap_xcd(int l, int mt, int& mtile, int& ntile) {
    int g  = l >> 6;
    int r  = l & 63;
    int gm = g << 3;
    if (gm + 8 <= mt) { mtile = gm + (r & 7); ntile = r >> 3; }
    else { int p = mt - gm; mtile = gm + (r % p); ntile = r / p; }  // tail group
}

// ---------------------------------------------------------------- utility kernels
__global__ void init_out_kernel(float* __restrict__ p, const float* __restrict__ b3, int n) {
    int i = blockIdx.x * blockDim.x + threadIdx.x;
    if (i < n) p[i] = b3[0];
}

// W1T[n*320 + p]: padded-triplet layout. p = t*32 + q; q<30 -> W1[(t*30+q)*1024 + n], else 0.
__global__ void transpose_w1_pad32(const float* __restrict__ W1, bf16* __restrict__ WT) {
    int idx = blockIdx.x * blockDim.x + threadIdx.x;
    if (idx >= 1024 * 320) return;
    int n = idx / 320;
    int p = idx - n * 320;
    int t = p >> 5;
    int q = p & 31;
    float v = (q < 30) ? W1[(size_t)(t * 30 + q) * 1024 + n] : 0.f;
    WT[idx] = f2b(v);
}

// Tiled transpose+cast for W2: WT[n*Kpad+k] = bf16(W[k*N+n]). 64x64 tiles via LDS.
__global__ __launch_bounds__(256)
void transpose_pad_tiled(const float* __restrict__ W, bf16* __restrict__ WT,
                         int K, int N, int Kpad) {
    __shared__ bf16 tile[64][65];
    const int t = threadIdx.x;
    const int tk = blockIdx.x * 64;
    const int tn = blockIdx.y * 64;
    #pragma unroll
    for (int r = 0; r < 16; ++r) {
        int kl = (t >> 6) + r * 4;
        int nl = t & 63;
        int k = tk + kl, n = tn + nl;
        float v = (k < K) ? W[(size_t)k * N + n] : 0.f;
        tile[kl][nl] = f2b(v);
    }
    __syncthreads();
    #pragma unroll
    for (int r = 0; r < 16; ++r) {
        int nl = (t >> 6) + r * 4;
        int kl = t & 63;
        WT[(size_t)(tn + nl) * Kpad + tk + kl] = tile[kl][nl];
    }
}

// ---------------------------------------------------------------- feature kernel (r8 winner + LDS gather fix)
__global__ __launch_bounds__(256)
void feat_kernel(const float* __restrict__ S, const float* __restrict__ E,
                 bf16* __restrict__ feat) {
    __shared__ bf16 sF[128 * 320];          // 80 KB
    float* sSE = (float*)sF;                // staging alias: S[3840] then E[1180]
    const int tid = threadIdx.x;
    const size_t r0 = (size_t)blockIdx.x * 128;
    const int row = tid >> 1, tp = tid & 1;

    // ---- stage S block (128x30 floats) and E (118x10 floats) into LDS ----
    {
        const float4* Sb = (const float4*)(S + r0 * 30);   // 16B-aligned (r0*120 B)
        #pragma unroll
        for (int i = 0; i < 4; ++i) {
            int idx = i * 256 + tid;                        // 960 float4 total
            if (idx < 960) ((float4*)sSE)[idx] = Sb[idx];
        }
        #pragma unroll
        for (int i = 0; i < 5; ++i) {
            int idx = i * 256 + tid;                        // 1180 floats
            if (idx < 1180) sSE[3840 + idx] = E[idx];
        }
    }
    __syncthreads();

    const float* sS = sSE;            // [128][30]
    const float* sE = sSE + 3840;     // [118][10]
    bf16x8 fr[5][4];
    #pragma unroll
    for (int c = 0; c < 5; ++c) {
        int t = c * 2 + tp;
        const float* sp = sS + row * 30 + t * 3;
        float fi = sp[0], fj = sp[1], d = sp[2];
        int ii = (int)fi;
        int jj = (int)fj;
        bf16 f[32];
        #pragma unroll
        for (int q = 0; q < 10; ++q) f[q]      = f2b((ii != 0) ? sE[ii * 10 + q] : 0.f);
        #pragma unroll
        for (int q = 0; q < 10; ++q) f[10 + q] = f2b((jj != 0) ? sE[jj * 10 + q] : 0.f);
        #pragma unroll
        for (int q = 0; q < 10; ++q) {
            float df = (float)(q + 1) * 0.7f - d;
            f[20 + q] = f2b((ii != 0) ? __expf(-df * df) : 0.f);   // GAMMA = 1
        }
        f[30] = f2b(0.f);
        f[31] = f2b(0.f);
        #pragma unroll
        for (int j = 0; j < 4; ++j) fr[c][j] = *(const bf16x8*)&f[j * 8];
    }
    __syncthreads();   // all S/E reads complete before sF overwrite

    #pragma unroll
    for (int c = 0; c < 5; ++c) {
        int t = c * 2 + tp;
        #pragma unroll
        for (int j = 0; j < 4; ++j) {
            int c0 = t * 4 + j;
            *(bf16x8*)&sF[row * 320 + ((c0 ^ (row & 7)) << 3)] = fr[c][j];
        }
    }
    __syncthreads();
    #pragma unroll
    for (int i = 0; i < 20; ++i) {
        int c2 = i * 256 + tid;        // 0..5119
        int r  = c2 / 40;
        int c  = c2 - r * 40;
        int p  = c ^ (r & 7);
        *(bf16x8*)(feat + r0 * 320 + (size_t)c2 * 8) = *(const bf16x8*)&sF[r * 320 + p * 8];
    }
}

// ---------------------------------------------------------------- MFMA GEMM
// C[M,N] = A[M,K] @ BT[N,K]^T ; 128x128 tile, BK=64, 4 waves (2x2), 4x4 16x16x32 frags.
// K-loop: r0/r8 verbatim. Both instantiations use __launch_bounds__(256,4) -- the
// r11 config (best measured: total 504, G2 213 us / MfmaUtil 44.7 / Occ 42%).
// r13 falsified the "G1 spills under the cap" theory (uncapping G1 -> 530 us).
// EPI==0 (G1): C = relu(acc+bias) staged via LDS as packed bf16 pairs (bank-
//   swizzled), stored fully coalesced dwordx4 (256B runs) -- replaces 64 scalar
//   2B stores/thread on the 268 MB X1c stream. Pack verified end-to-end in r4.
// EPI==1 (G2): relu-dot-w3, 16-lane shuffle reduce, atomicAdd into out (r11 form).
template <int EPI, int KTOTAL>
__global__ __launch_bounds__(256, 4)
void gemm_kernel(const bf16* __restrict__ A, const bf16* __restrict__ BT,
                 const float* __restrict__ bias, bf16* __restrict__ C,
                 float* __restrict__ outf, const float* __restrict__ w3,
                 int lda, int ldbt, int ldc, int mt) {
    __shared__ __align__(16) bf16 sAB[2 * 128 * 64];
    bf16* sA = sAB;
    bf16* sB = sAB + 128 * 64;
    const int tid  = threadIdx.x;
    const int lane = tid & 63;
    const int wave = tid >> 6;
    const int wr = wave >> 1, wc = wave & 1;
    const int l16 = lane & 15, quad = lane >> 4;
    int mtile, ntile;
    remap_xcd(blockIdx.x, mt, mtile, ntile);
    const size_t m0 = (size_t)mtile * 128;
    const int    n0 = ntile * 128;

    // loop-invariant staging bases (kk enters as an immediate offset after unroll)
    const bf16* gA[4];
    const bf16* gB[4];
    #pragma unroll
    for (int i = 0; i < 4; ++i) {
        int s   = i * 256 + tid;
        int row = s >> 3;
        int kof = (((s & 7) ^ (row & 7)) << 3);
        gA[i] = A  + (m0 + row) * lda          + kof;
        gB[i] = BT + (size_t)(n0 + row) * ldbt + kof;
    }

    f32x4 acc[4][4];
    #pragma unroll
    for (int i = 0; i < 4; ++i)
        #pragma unroll
        for (int j = 0; j < 4; ++j) acc[i][j] = (f32x4){0.f, 0.f, 0.f, 0.f};

    #pragma unroll
    for (int kk = 0; kk < KTOTAL; kk += 64) {
        #pragma unroll
        for (int i = 0; i < 4; ++i) {
            int s = i * 256 + tid;
            async_copy16(gA[i] + kk, &sA[s * 8]);
            async_copy16(gB[i] + kk, &sB[s * 8]);
        }
        __syncthreads();
        #pragma unroll
        for (int s2 = 0; s2 < 2; ++s2) {
            int clog = s2 * 4 + quad;
            bf16x8 a[4], b[4];
            #pragma unroll
            for (int mi = 0; mi < 4; ++mi) {
                int r = wr * 64 + mi * 16 + l16;
                a[mi] = *(const bf16x8*)&sA[r * 64 + ((clog ^ (r & 7)) << 3)];
            }
            #pragma unroll
            for (int ni = 0; ni < 4; ++ni) {
                int r = wc * 64 + ni * 16 + l16;
                b[ni] = *(const bf16x8*)&sB[r * 64 + ((clog ^ (r & 7)) << 3)];
            }
            #pragma unroll
            for (int mi = 0; mi < 4; ++mi)
                #pragma unroll
                for (int ni = 0; ni < 4; ++ni)
                    acc[mi][ni] = __builtin_amdgcn_mfma_f32_16x16x32_bf16(
                        a[mi], b[ni], acc[mi][ni], 0, 0, 0);
        }
        __syncthreads();
    }

    if (EPI == 0) {
        // ---- pack relu(acc+bias) into LDS as bf16 pairs, bank-swizzled (r4-verified) ----
        uint32_t* sCw = (uint32_t*)sAB;
        #pragma unroll
        for (int ni = 0; ni < 4; ++ni) {
            int col = n0 + wc * 64 + ni * 16 + l16;
            float bv = bias[col];
            #pragma unroll
            for (int mi = 0; mi < 4; ++mi) {
                int rowb = wr * 64 + mi * 16 + quad * 4;
                int cpb  = (wc * 64 + ni * 16 + (l16 & 14)) >> 1;
                #pragma unroll
                for (int r = 0; r < 4; ++r) {
                    float v = acc[mi][ni][r] + bv;
                    v = v > 0.f ? v : 0.f;
                    float vp = __shfl_xor(v, 1);
                    uint32_t lo = (l16 & 1) ? b16bits(vp) : b16bits(v);
                    uint32_t hi = (l16 & 1) ? b16bits(v)  : b16bits(vp);
                    uint32_t pk = lo | (hi << 16);
                    int row = rowb + r;
                    int cp  = cpb ^ (((row >> 2) & 7) << 3);
                    if ((l16 & 1) == 0) sCw[row * 64 + cp] = pk;
                }
            }
        }
        __syncthreads();
        // ---- coalesced store: 16 lanes cover one 256B row segment ----
        const int rb = tid >> 4;           // 0..15
        const int cs = tid & 15;           // 16B segment within row
        #pragma unroll
        for (int p = 0; p < 8; ++p) {
            int row = rb + p * 16;
            int cp  = (cs * 4) ^ (((row >> 2) & 7) << 3);
            u32x4 w = *(const u32x4*)&sCw[row * 64 + cp];
            *(u32x4*)(C + (m0 + row) * ldc + n0 + cs * 8) = w;
        }
    } else {
        #pragma unroll
        for (int mi = 0; mi < 4; ++mi) {
            #pragma unroll
            for (int r = 0; r < 4; ++r) {
                float p = 0.f;
                #pragma unroll
                for (int ni = 0; ni < 4; ++ni) {
                    int col = n0 + wc * 64 + ni * 16 + l16;
                    float v = acc[mi][ni][r] + bias[col];
                    v = v > 0.f ? v : 0.f;
                    p += v * w3[col];
                }
                #pragma unroll
                for (int off = 1; off < 16; off <<= 1)
                    p += __shfl_xor(p, off, 64);
                if (l16 == 0) {
                    size_t row = m0 + wr * 64 + mi * 16 + quad * 4 + r;
                    atomicAdd(&outf[row], p);
                }
            }
        }
    }
}

// ---------------------------------------------------------------- zero-workspace fallback
#define FB_ROWS 8
__global__ __launch_bounds__(256)
void fallback_kernel(const float* __restrict__ S, const float* __restrict__ E,
                     const float* __restrict__ W1, const float* __restrict__ b1,
                     const float* __restrict__ W2, const float* __restrict__ b2,
                     const float* __restrict__ W3, const float* __restrict__ b3,
                     float* __restrict__ out) {
    __shared__ float feat[FB_ROWS][304];
    __shared__ float X1[FB_ROWS][1024];
    __shared__ float red[256];
    const int tid = threadIdx.x;
    const size_t r0 = (size_t)blockIdx.x * FB_ROWS;

    if (tid < FB_ROWS * 10) {
        int r = tid / 10, t = tid - r * 10;
        const float* s = S + (r0 + r) * 30 + t * 3;
        float fi = s[0], fj = s[1], d = s[2];
        int ii = (int)fi;
        int jj = (int)fj;
        float* o = &feat[r][t * 30];
        #pragma unroll
        for (int c = 0; c < 10; ++c) o[c]      = (ii != 0) ? E[ii * 10 + c] : 0.f;
        #pragma unroll
        for (int c = 0; c < 10; ++c) o[10 + c] = (jj != 0) ? E[jj * 10 + c] : 0.f;
        #pragma unroll
        for (int c = 0; c < 10; ++c) {
            float df = (float)(c + 1) * 0.7f - d;
            o[20 + c] = (ii != 0) ? __expf(-df * df) : 0.f;
        }
    }
    __syncthreads();

    for (int i = 0; i < FB_ROWS * 1024 / 256; ++i) {
        int idx = i * 256 + tid;
        int r = idx & (FB_ROWS - 1);
        int c = idx >> 3;
        float a = b1[c];
        for (int k = 0; k < 300; ++k)
            a += feat[r][k] * W1[(size_t)k * 1024 + c];
        X1[r][c] = a > 0.f ? a : 0.f;
    }
    __syncthreads();

    {
        int r  = tid & (FB_ROWS - 1);
        int cg = tid >> 3;
        float acc = 0.f;
        for (int cc = 0; cc < 32; ++cc) {
            int c = cg * 32 + cc;
            float a = b2[c];
            for (int k = 0; k < 1024; ++k)
                a += X1[r][k] * W2[(size_t)k * 1024 + c];
            a = a > 0.f ? a : 0.f;
            acc += a * W3[c];
        }
        red[tid] = acc;
    }
    __syncthreads();
    if (tid < FB_ROWS) {
        float s = 0.f;
        for (int g = 0; g < 32; ++g) s += red[g * FB_ROWS + tid];
        out[r0 + tid] = s + b3[0];
    }
}

// ---------------------------------------------------------------- launch
extern "C" void kernel_launch(void* const* d_in, const int* in_sizes, int n_in,
                              void* d_out, int out_size, void* d_ws, size_t ws_size,
                              hipStream_t stream) {
    const float* S  = (const float*)d_in[0];
    const float* E  = (const float*)d_in[1];
    const float* W1 = (const float*)d_in[2];
    const float* b1 = (const float*)d_in[3];
    const float* W2 = (const float*)d_in[4];
    const float* b2 = (const float*)d_in[5];
    const float* W3 = (const float*)d_in[6];
    const float* b3 = (const float*)d_in[7];
    float* out = (float*)d_out;

    const int Bn  = out_size;   // 131072
    const int HID = 1024;
    const int K1  = 320;

    const size_t MIN_WS = 16u * 1024u * 1024u;
    if (ws_size < MIN_WS) {
        fallback_kernel<<<Bn / FB_ROWS, 256, 0, stream>>>(S, E, W1, b1, W2, b2, W3, b3, out);
        return;
    }

    char* ws = (char*)d_ws;
    size_t off = 0;
    auto take = [&](size_t bytes) { char* p = ws + off; off += (bytes + 255) & ~(size_t)255; return p; };
    bf16* W1T = (bf16*)take((size_t)HID * K1 * sizeof(bf16));
    bf16* W2T = (bf16*)take((size_t)HID * HID * sizeof(bf16));

    size_t avail   = ws_size - off - 256;
    size_t per_row = (size_t)K1 * sizeof(bf16) + (size_t)HID * sizeof(bf16); // 2688 B
    size_t chunk   = (avail / per_row) & ~(size_t)1023;   // multiple of 1024 rows
    if (chunk > (size_t)Bn) chunk = Bn;
    bf16* featc = (bf16*)take(chunk * K1 * sizeof(bf16));
    bf16* X1c   = (bf16*)take(chunk * HID * sizeof(bf16));

    init_out_kernel<<<(Bn + 255) / 256, 256, 0, stream>>>(out, b3, Bn);
    transpose_w1_pad32<<<(HID * K1 + 255) / 256, 256, 0, stream>>>(W1, W1T);
    {
        dim3 g2(HID / 64, HID / 64);
        transpose_pad_tiled<<<g2, 256, 0, stream>>>(W2, W2T, HID, HID, HID);
    }

    for (size_t r0 = 0; r0 < (size_t)Bn; r0 += chunk) {
        size_t rows = ((size_t)Bn - r0 < chunk) ? ((size_t)Bn - r0) : chunk;
        int mt = (int)(rows / 128);
        feat_kernel<<<(unsigned)(rows / 128), 256, 0, stream>>>(S + r0 * 30, E, featc);
        gemm_kernel<0, 320><<<(unsigned)(mt * 8), 256, 0, stream>>>(
            featc, W1T, b1, X1c, nullptr, nullptr, K1, K1, HID, mt);
        gemm_kernel<1, 1024><<<(unsigned)(mt * 8), 256, 0, stream>>>(
            X1c, W2T, b2, nullptr, out + r0, W3, HID, HID, 0, mt);
    }
}

// Round 15
// 492.829 us; speedup vs baseline: 1.1201x; 1.1201x over previous
//
#include <hip/hip_runtime.h>
#include <hip/hip_bf16.h>
#include <stdint.h>
#include <stddef.h>

typedef __hip_bfloat16 bf16;
typedef __attribute__((ext_vector_type(8))) __bf16 bf16x8;
typedef __attribute__((ext_vector_type(4))) float f32x4;

__device__ __forceinline__ bf16 f2b(float x) { return __float2bfloat16(x); }

// async global->LDS copy, 16B per lane. LDS dest must be wave-uniform base + lane*16.
__device__ __forceinline__ void async_copy16(const bf16* g, bf16* l) {
    __builtin_amdgcn_global_load_lds(
        (const __attribute__((address_space(1))) unsigned int*)g,
        (__attribute__((address_space(3))) unsigned int*)l,
        16, 0, 0);
}

// XCD-aware remap: blocks dispatch round-robin to 8 XCDs by l%8. Map each group of
// 64 consecutive l to 8 m-tiles x 8 n-tiles so the 8 blocks of one XCD share ONE
// m-tile -> A row-tile fetched once into that XCD's L2.
__device__ __forceinline__ void remap_xcd(int l, int mt, int& mtile, int& ntile) {
    int g  = l >> 6;
    int r  = l & 63;
    int gm = g << 3;
    if (gm + 8 <= mt) { mtile = gm + (r & 7); ntile = r >> 3; }
    else { int p = mt - gm; mtile = gm + (r % p); ntile = r / p; }  // tail group
}

// ---------------------------------------------------------------- utility kernels
__global__ void init_out_kernel(float* __restrict__ p, const float* __restrict__ b3, int n) {
    int i = blockIdx.x * blockDim.x + threadIdx.x;
    if (i < n) p[i] = b3[0];
}

// W1T[n*320 + p]: padded-triplet layout. p = t*32 + q; q<30 -> W1[(t*30+q)*1024 + n], else 0.
__global__ void transpose_w1_pad32(const float* __restrict__ W1, bf16* __restrict__ WT) {
    int idx = blockIdx.x * blockDim.x + threadIdx.x;
    if (idx >= 1024 * 320) return;
    int n = idx / 320;
    int p = idx - n * 320;
    int t = p >> 5;
    int q = p & 31;
    float v = (q < 30) ? W1[(size_t)(t * 30 + q) * 1024 + n] : 0.f;
    WT[idx] = f2b(v);
}

// Tiled transpose+cast for W2: WT[n*Kpad+k] = bf16(W[k*N+n]). 64x64 tiles via LDS.
__global__ __launch_bounds__(256)
void transpose_pad_tiled(const float* __restrict__ W, bf16* __restrict__ WT,
                         int K, int N, int Kpad) {
    __shared__ bf16 tile[64][65];
    const int t = threadIdx.x;
    const int tk = blockIdx.x * 64;
    const int tn = blockIdx.y * 64;
    #pragma unroll
    for (int r = 0; r < 16; ++r) {
        int kl = (t >> 6) + r * 4;
        int nl = t & 63;
        int k = tk + kl, n = tn + nl;
        float v = (k < K) ? W[(size_t)k * N + n] : 0.f;
        tile[kl][nl] = f2b(v);
    }
    __syncthreads();
    #pragma unroll
    for (int r = 0; r < 16; ++r) {
        int nl = (t >> 6) + r * 4;
        int kl = t & 63;
        WT[(size_t)(tn + nl) * Kpad + tk + kl] = tile[kl][nl];
    }
}

// ---------------------------------------------------------------- feature kernel (r8 winner + LDS gather fix)
__global__ __launch_bounds__(256)
void feat_kernel(const float* __restrict__ S, const float* __restrict__ E,
                 bf16* __restrict__ feat) {
    __shared__ bf16 sF[128 * 320];          // 80 KB
    float* sSE = (float*)sF;                // staging alias: S[3840] then E[1180]
    const int tid = threadIdx.x;
    const size_t r0 = (size_t)blockIdx.x * 128;
    const int row = tid >> 1, tp = tid & 1;

    // ---- stage S block (128x30 floats) and E (118x10 floats) into LDS ----
    {
        const float4* Sb = (const float4*)(S + r0 * 30);   // 16B-aligned (r0*120 B)
        #pragma unroll
        for (int i = 0; i < 4; ++i) {
            int idx = i * 256 + tid;                        // 960 float4 total
            if (idx < 960) ((float4*)sSE)[idx] = Sb[idx];
        }
        #pragma unroll
        for (int i = 0; i < 5; ++i) {
            int idx = i * 256 + tid;                        // 1180 floats
            if (idx < 1180) sSE[3840 + idx] = E[idx];
        }
    }
    __syncthreads();

    const float* sS = sSE;            // [128][30]
    const float* sE = sSE + 3840;     // [118][10]
    bf16x8 fr[5][4];
    #pragma unroll
    for (int c = 0; c < 5; ++c) {
        int t = c * 2 + tp;
        const float* sp = sS + row * 30 + t * 3;
        float fi = sp[0], fj = sp[1], d = sp[2];
        int ii = (int)fi;
        int jj = (int)fj;
        bf16 f[32];
        #pragma unroll
        for (int q = 0; q < 10; ++q) f[q]      = f2b((ii != 0) ? sE[ii * 10 + q] : 0.f);
        #pragma unroll
        for (int q = 0; q < 10; ++q) f[10 + q] = f2b((jj != 0) ? sE[jj * 10 + q] : 0.f);
        #pragma unroll
        for (int q = 0; q < 10; ++q) {
            float df = (float)(q + 1) * 0.7f - d;
            f[20 + q] = f2b((ii != 0) ? __expf(-df * df) : 0.f);   // GAMMA = 1
        }
        f[30] = f2b(0.f);
        f[31] = f2b(0.f);
        #pragma unroll
        for (int j = 0; j < 4; ++j) fr[c][j] = *(const bf16x8*)&f[j * 8];
    }
    __syncthreads();   // all S/E reads complete before sF overwrite

    #pragma unroll
    for (int c = 0; c < 5; ++c) {
        int t = c * 2 + tp;
        #pragma unroll
        for (int j = 0; j < 4; ++j) {
            int c0 = t * 4 + j;
            *(bf16x8*)&sF[row * 320 + ((c0 ^ (row & 7)) << 3)] = fr[c][j];
        }
    }
    __syncthreads();
    #pragma unroll
    for (int i = 0; i < 20; ++i) {
        int c2 = i * 256 + tid;        // 0..5119
        int r  = c2 / 40;
        int c  = c2 - r * 40;
        int p  = c ^ (r & 7);
        *(bf16x8*)(feat + r0 * 320 + (size_t)c2 * 8) = *(const bf16x8*)&sF[r * 320 + p * 8];
    }
}

// ---------------------------------------------------------------- MFMA GEMM (best-measured config, r11)
// C[M,N] = A[M,K] @ BT[N,K]^T ; 128x128 tile, BK=64, 4 waves (2x2), 4x4 16x16x32 frags.
// K-loop: r0/r8 verbatim (stage -> sync -> compute -> sync; KTOTAL compile-time ->
// fully unrolled, base+imm addressing). XCD-aware 1-D grid.
// __launch_bounds__(256, 4) on BOTH instantiations: caps regs at 128/wave (VGPR 64 +
// 64 AGPR acc) -> 4 blocks/CU. Measured: G2 225 -> 213 us, MfmaUtil 44.7, Occ 42%.
// Session-closed levers (each measured worse): 8-phase/256-tile (r1/r2), dbuf
// 1-barrier (r9), G1 feat-fusion (r6/r7), plane-store G2 epilogue (r4), LDS-packed
// G1 C-store (r14), split launch bounds (r13).
// EPI==0: C = relu(acc + bias) stored bf16.   EPI==1: out[row] += relu-dot-w3 (atomic).
template <int EPI, int KTOTAL>
__global__ __launch_bounds__(256, 4)
void gemm_kernel(const bf16* __restrict__ A, const bf16* __restrict__ BT,
                 const float* __restrict__ bias, bf16* __restrict__ C,
                 float* __restrict__ outf, const float* __restrict__ w3,
                 int lda, int ldbt, int ldc, int mt) {
    __shared__ bf16 sA[128 * 64];
    __shared__ bf16 sB[128 * 64];
    const int tid  = threadIdx.x;
    const int lane = tid & 63;
    const int wave = tid >> 6;
    const int wr = wave >> 1, wc = wave & 1;
    const int l16 = lane & 15, quad = lane >> 4;
    int mtile, ntile;
    remap_xcd(blockIdx.x, mt, mtile, ntile);
    const size_t m0 = (size_t)mtile * 128;
    const int    n0 = ntile * 128;

    // loop-invariant staging bases (kk enters as an immediate offset after unroll)
    const bf16* gA[4];
    const bf16* gB[4];
    #pragma unroll
    for (int i = 0; i < 4; ++i) {
        int s   = i * 256 + tid;
        int row = s >> 3;
        int kof = (((s & 7) ^ (row & 7)) << 3);
        gA[i] = A  + (m0 + row) * lda          + kof;
        gB[i] = BT + (size_t)(n0 + row) * ldbt + kof;
    }

    f32x4 acc[4][4];
    #pragma unroll
    for (int i = 0; i < 4; ++i)
        #pragma unroll
        for (int j = 0; j < 4; ++j) acc[i][j] = (f32x4){0.f, 0.f, 0.f, 0.f};

    #pragma unroll
    for (int kk = 0; kk < KTOTAL; kk += 64) {
        #pragma unroll
        for (int i = 0; i < 4; ++i) {
            int s = i * 256 + tid;
            async_copy16(gA[i] + kk, &sA[s * 8]);
            async_copy16(gB[i] + kk, &sB[s * 8]);
        }
        __syncthreads();
        #pragma unroll
        for (int s2 = 0; s2 < 2; ++s2) {
            int clog = s2 * 4 + quad;
            bf16x8 a[4], b[4];
            #pragma unroll
            for (int mi = 0; mi < 4; ++mi) {
                int r = wr * 64 + mi * 16 + l16;
                a[mi] = *(const bf16x8*)&sA[r * 64 + ((clog ^ (r & 7)) << 3)];
            }
            #pragma unroll
            for (int ni = 0; ni < 4; ++ni) {
                int r = wc * 64 + ni * 16 + l16;
                b[ni] = *(const bf16x8*)&sB[r * 64 + ((clog ^ (r & 7)) << 3)];
            }
            #pragma unroll
            for (int mi = 0; mi < 4; ++mi)
                #pragma unroll
                for (int ni = 0; ni < 4; ++ni)
                    acc[mi][ni] = __builtin_amdgcn_mfma_f32_16x16x32_bf16(
                        a[mi], b[ni], acc[mi][ni], 0, 0, 0);
        }
        __syncthreads();
    }

    if (EPI == 0) {
        #pragma unroll
        for (int mi = 0; mi < 4; ++mi) {
            #pragma unroll
            for (int ni = 0; ni < 4; ++ni) {
                int col = n0 + wc * 64 + ni * 16 + l16;
                float bv = bias[col];
                #pragma unroll
                for (int r = 0; r < 4; ++r) {
                    size_t row = m0 + wr * 64 + mi * 16 + quad * 4 + r;
                    float v = acc[mi][ni][r] + bv;
                    v = v > 0.f ? v : 0.f;
                    C[row * ldc + col] = f2b(v);
                }
            }
        }
    } else {
        #pragma unroll
        for (int mi = 0; mi < 4; ++mi) {
            #pragma unroll
            for (int r = 0; r < 4; ++r) {
                float p = 0.f;
                #pragma unroll
                for (int ni = 0; ni < 4; ++ni) {
                    int col = n0 + wc * 64 + ni * 16 + l16;
                    float v = acc[mi][ni][r] + bias[col];
                    v = v > 0.f ? v : 0.f;
                    p += v * w3[col];
                }
                #pragma unroll
                for (int off = 1; off < 16; off <<= 1)
                    p += __shfl_xor(p, off, 64);
                if (l16 == 0) {
                    size_t row = m0 + wr * 64 + mi * 16 + quad * 4 + r;
                    atomicAdd(&outf[row], p);
                }
            }
        }
    }
}

// ---------------------------------------------------------------- zero-workspace fallback
#define FB_ROWS 8
__global__ __launch_bounds__(256)
void fallback_kernel(const float* __restrict__ S, const float* __restrict__ E,
                     const float* __restrict__ W1, const float* __restrict__ b1,
                     const float* __restrict__ W2, const float* __restrict__ b2,
                     const float* __restrict__ W3, const float* __restrict__ b3,
                     float* __restrict__ out) {
    __shared__ float feat[FB_ROWS][304];
    __shared__ float X1[FB_ROWS][1024];
    __shared__ float red[256];
    const int tid = threadIdx.x;
    const size_t r0 = (size_t)blockIdx.x * FB_ROWS;

    if (tid < FB_ROWS * 10) {
        int r = tid / 10, t = tid - r * 10;
        const float* s = S + (r0 + r) * 30 + t * 3;
        float fi = s[0], fj = s[1], d = s[2];
        int ii = (int)fi;
        int jj = (int)fj;
        float* o = &feat[r][t * 30];
        #pragma unroll
        for (int c = 0; c < 10; ++c) o[c]      = (ii != 0) ? E[ii * 10 + c] : 0.f;
        #pragma unroll
        for (int c = 0; c < 10; ++c) o[10 + c] = (jj != 0) ? E[jj * 10 + c] : 0.f;
        #pragma unroll
        for (int c = 0; c < 10; ++c) {
            float df = (float)(c + 1) * 0.7f - d;
            o[20 + c] = (ii != 0) ? __expf(-df * df) : 0.f;
        }
    }
    __syncthreads();

    for (int i = 0; i < FB_ROWS * 1024 / 256; ++i) {
        int idx = i * 256 + tid;
        int r = idx & (FB_ROWS - 1);
        int c = idx >> 3;
        float a = b1[c];
        for (int k = 0; k < 300; ++k)
            a += feat[r][k] * W1[(size_t)k * 1024 + c];
        X1[r][c] = a > 0.f ? a : 0.f;
    }
    __syncthreads();

    {
        int r  = tid & (FB_ROWS - 1);
        int cg = tid >> 3;
        float acc = 0.f;
        for (int cc = 0; cc < 32; ++cc) {
            int c = cg * 32 + cc;
            float a = b2[c];
            for (int k = 0; k < 1024; ++k)
                a += X1[r][k] * W2[(size_t)k * 1024 + c];
            a = a > 0.f ? a : 0.f;
            acc += a * W3[c];
        }
        red[tid] = acc;
    }
    __syncthreads();
    if (tid < FB_ROWS) {
        float s = 0.f;
        for (int g = 0; g < 32; ++g) s += red[g * FB_ROWS + tid];
        out[r0 + tid] = s + b3[0];
    }
}

// ---------------------------------------------------------------- launch
extern "C" void kernel_launch(void* const* d_in, const int* in_sizes, int n_in,
                              void* d_out, int out_size, void* d_ws, size_t ws_size,
                              hipStream_t stream) {
    const float* S  = (const float*)d_in[0];
    const float* E  = (const float*)d_in[1];
    const float* W1 = (const float*)d_in[2];
    const float* b1 = (const float*)d_in[3];
    const float* W2 = (const float*)d_in[4];
    const float* b2 = (const float*)d_in[5];
    const float* W3 = (const float*)d_in[6];
    const float* b3 = (const float*)d_in[7];
    float* out = (float*)d_out;

    const int Bn  = out_size;   // 131072
    const int HID = 1024;
    const int K1  = 320;

    const size_t MIN_WS = 16u * 1024u * 1024u;
    if (ws_size < MIN_WS) {
        fallback_kernel<<<Bn / FB_ROWS, 256, 0, stream>>>(S, E, W1, b1, W2, b2, W3, b3, out);
        return;
    }

    char* ws = (char*)d_ws;
    size_t off = 0;
    auto take = [&](size_t bytes) { char* p = ws + off; off += (bytes + 255) & ~(size_t)255; return p; };
    bf16* W1T = (bf16*)take((size_t)HID * K1 * sizeof(bf16));
    bf16* W2T = (bf16*)take((size_t)HID * HID * sizeof(bf16));

    size_t avail   = ws_size - off - 256;
    size_t per_row = (size_t)K1 * sizeof(bf16) + (size_t)HID * sizeof(bf16); // 2688 B
    size_t chunk   = (avail / per_row) & ~(size_t)1023;   // multiple of 1024 rows
    if (chunk > (size_t)Bn) chunk = Bn;
    bf16* featc = (bf16*)take(chunk * K1 * sizeof(bf16));
    bf16* X1c   = (bf16*)take(chunk * HID * sizeof(bf16));

    init_out_kernel<<<(Bn + 255) / 256, 256, 0, stream>>>(out, b3, Bn);
    transpose_w1_pad32<<<(HID * K1 + 255) / 256, 256, 0, stream>>>(W1, W1T);
    {
        dim3 g2(HID / 64, HID / 64);
        transpose_pad_tiled<<<g2, 256, 0, stream>>>(W2, W2T, HID, HID, HID);
    }

    for (size_t r0 = 0; r0 < (size_t)Bn; r0 += chunk) {
        size_t rows = ((size_t)Bn - r0 < chunk) ? ((size_t)Bn - r0) : chunk;
        int mt = (int)(rows / 128);
        feat_kernel<<<(unsigned)(rows / 128), 256, 0, stream>>>(S + r0 * 30, E, featc);
        gemm_kernel<0, 320><<<(unsigned)(mt * 8), 256, 0, stream>>>(
            featc, W1T, b1, X1c, nullptr, nullptr, K1, K1, HID, mt);
        gemm_kernel<1, 1024><<<(unsigned)(mt * 8), 256, 0, stream>>>(
            X1c, W2T, b2, nullptr, out + r0, W3, HID, HID, 0, mt);
    }
}